// Round 4
// baseline (7688.737 us; speedup 1.0000x reference)
//
#include <hip/hip_runtime.h>

// ============================================================================
// 2-layer LSTM (B=64,T=512,I=256,H=1024) + head. Persistent kernel, R4.
//
// R4 vs R3 (14.7 us/stage: L2 weight thrash + 8B-atomic LLC request storm +
// tree-barrier RTTs):
//  * WEIGHTS IN REGISTERS: each wave preloads its 10/16 B-fragments (40/64
//    VGPR) once before the 512-step loop. Per-stage weight memory traffic = 0.
//    L2 thrash impossible regardless of XCD mapping.
//  * h exchange via volatile 16B loads/stores (sc0+sc1 on gfx95x): coherent
//    through LLC like R3's agent atomics, but line-coalesced plain-load path
//    (2x fewer LLC transactions) and compiler-managed waitcnt.
//  * FLAT per-layer barrier: single 128-arrive counter (adds pipeline at LLC)
//    + 4 spread release-flag lines; FIFO admission spin done per-WG BEFORE
//    arrival (off the release critical path).
//  * lay = (wg>>3)&1 interleave: balances layers across XCDs under both %8
//    and /32 block->XCD mappings.
//  * x pre-packed to fp16 MFMA-fragment layout (skipped if ws too small).
//
// Workspace:
//   0         W0pack fp16 [128][40][2][512]   10,485,760 B
//   10485760  W1pack fp16 [128][64][2][512]   16,777,216 B
//   27262976  h0q    fp16 4 slots x 128 KB       524,288 B
//   27787264  h2q    fp16 2 slots x 128 KB       262,144 B
//   28049408  sync   uint[2048]                    8,192 B
//   28057600  xpk    fp16 [512][16384]         16,777,216 B   (optional)
// ============================================================================

typedef _Float16 h8 __attribute__((ext_vector_type(8)));
typedef float    f4 __attribute__((ext_vector_type(4)));
typedef unsigned long long u64;

#define WS_W0PACK 0
#define WS_W1PACK 10485760
#define WS_H0Q    27262976
#define WS_H2Q    27787264
#define WS_SYNC   28049408
#define WS_XPK    28057600
#define WS_XPK_END 44834816ULL

static __device__ __forceinline__ float sigm(float v) { return 1.f / (1.f + __expf(-v)); }
static __device__ __forceinline__ float tanh_fast(float v) {
  const float e = __expf(2.f * v);
  return 1.f - 2.f / (e + 1.f);
}
static __device__ __forceinline__ unsigned ld_flag(const unsigned* p) {
  return __hip_atomic_load(p, __ATOMIC_RELAXED, __HIP_MEMORY_SCOPE_AGENT);
}
static __device__ __forceinline__ h8 vload16(const _Float16* p) {
  return *(const volatile h8*)p;          // global_load_dwordx4 sc0 sc1
}
static __device__ __forceinline__ void vstore16(_Float16* p, h8 v) {
  *(volatile h8*)p = v;                   // global_store_dwordx4 sc0 sc1
}

// ---------------------------------------------------------------------------
__global__ void prep_kernel(const float* __restrict__ x,
                            const float* __restrict__ Wih0, const float* __restrict__ Whh0,
                            const float* __restrict__ Wih1, const float* __restrict__ Whh1,
                            _Float16* __restrict__ W0p, _Float16* __restrict__ W1p,
                            _Float16* __restrict__ xpk,
                            unsigned* __restrict__ hz, unsigned* __restrict__ sync_ws)
{
  for (int wgl = blockIdx.x; wgl < 128; wgl += gridDim.x) {
    unsigned* d0 = (unsigned*)(W0p + (long)wgl * 40960);
    for (int t = threadIdx.x; t < 20480; t += blockDim.x) {
      const int j2 = t & 3, quad = (t >> 2) & 3, l15 = (t >> 4) & 15;
      const int colt = (t >> 8) & 1, c = t >> 9;
      const int cc = colt * 16 + l15;
      const int row = ((cc >> 3) << 10) + wgl * 8 + (cc & 7);
      const int k = c * 32 + quad * 8 + j2 * 2;
      float a, b;
      if (k < 256) { a = Wih0[(long)row * 256 + k];        b = Wih0[(long)row * 256 + k + 1]; }
      else         { a = Whh0[(long)row * 1024 + k - 256]; b = Whh0[(long)row * 1024 + k - 255]; }
      union { unsigned u; _Float16 h[2]; } o;
      o.h[0] = (_Float16)a; o.h[1] = (_Float16)b;
      d0[t] = o.u;
    }
    unsigned* d1 = (unsigned*)(W1p + (long)wgl * 65536);
    for (int t = threadIdx.x; t < 32768; t += blockDim.x) {
      const int j2 = t & 3, quad = (t >> 2) & 3, l15 = (t >> 4) & 15;
      const int colt = (t >> 8) & 1, c = t >> 9;
      const int cc = colt * 16 + l15;
      const int row = ((cc >> 3) << 10) + wgl * 8 + (cc & 7);
      const int k = c * 32 + quad * 8 + j2 * 2;
      float a, b;
      if (k < 1024) { a = Wih1[(long)row * 1024 + k];        b = Wih1[(long)row * 1024 + k + 1]; }
      else          { a = Whh1[(long)row * 1024 + k - 1024]; b = Whh1[(long)row * 1024 + k - 1023]; }
      union { unsigned u; _Float16 h[2]; } o;
      o.h[0] = (_Float16)a; o.h[1] = (_Float16)b;
      d1[t] = o.u;
    }
  }
  const long tid0 = (long)blockIdx.x * blockDim.x + threadIdx.x;
  const long np   = (long)gridDim.x * blockDim.x;
  if (xpk) {                                  // x -> fp16 fragment layout
    for (long e = tid0; e < 8388608; e += np) {
      const int t = (int)(e >> 14), i = (int)(e & 16383);
      const int c = i >> 11, r = (i >> 9) & 3, b15 = (i >> 5) & 15;
      const int quad = (i >> 3) & 3, j = i & 7;
      const int b = r * 16 + b15, k = c * 32 + quad * 8 + j;
      xpk[e] = (_Float16)x[(long)b * 131072 + (long)t * 256 + k];
    }
  }
  for (long e = tid0; e < 196608; e += np) hz[e] = 0u;   // h0q + h2q
  if (tid0 < 2048) sync_ws[tid0] = 0u;
}

// ---------------------------------------------------------------------------
static __device__ __forceinline__ void consume(const h8 A[4], const h8 B0, const h8 B1,
                                               f4 (&acc)[4][2])
{
#pragma unroll
  for (int r = 0; r < 4; ++r) {
    acc[r][0] = __builtin_amdgcn_mfma_f32_16x16x32_f16(A[r], B0, acc[r][0], 0, 0, 0);
    acc[r][1] = __builtin_amdgcn_mfma_f32_16x16x32_f16(A[r], B1, acc[r][1], 0, 0, 0);
  }
}

template<bool XP>
static __device__ __forceinline__ void loadA0(int c, const float* __restrict__ x,
                                              const _Float16* __restrict__ xt, int n,
                                              const _Float16* h0rd, int lofs,
                                              int l15, int quad, h8 A[4])
{
  if (c < 8) {
    if (XP) {
      const _Float16* ap = xt + c * 2048 + lofs;
#pragma unroll
      for (int r = 0; r < 4; ++r) A[r] = *(const h8*)(ap + r * 512);
    } else {
      const int kq = c * 32 + quad * 8;
      const float* xp = x + (long)n * 256 + (long)l15 * 131072 + kq;
#pragma unroll
      for (int r = 0; r < 4; ++r) {
        const float* q = xp + (long)r * 16 * 131072;
        const f4 v0 = *(const f4*)q;
        const f4 v1 = *(const f4*)(q + 4);
        h8 t;
        t[0]=(_Float16)v0[0]; t[1]=(_Float16)v0[1]; t[2]=(_Float16)v0[2]; t[3]=(_Float16)v0[3];
        t[4]=(_Float16)v1[0]; t[5]=(_Float16)v1[1]; t[6]=(_Float16)v1[2]; t[7]=(_Float16)v1[3];
        A[r] = t;
      }
    }
  } else {
    const _Float16* hb = h0rd + (c - 8) * 2048 + lofs;
#pragma unroll
    for (int r = 0; r < 4; ++r) A[r] = vload16(hb + r * 512);
  }
}

static __device__ __forceinline__ void loadA1(int c, const _Float16* h0rd,
                                              const _Float16* h2rd, int lofs, h8 A[4])
{
  const _Float16* hb = (c < 32) ? (h0rd + c * 2048 + lofs)
                                : (h2rd + (c - 32) * 2048 + lofs);
#pragma unroll
  for (int r = 0; r < 4; ++r) A[r] = vload16(hb + r * 512);
}

// ---------------------------------------------------------------------------
template<bool XP>
__launch_bounds__(512, 1)
__global__ void lstm_kernel(const float* __restrict__ x, const _Float16* __restrict__ xpk,
                            const float* __restrict__ bih0, const float* __restrict__ bhh0,
                            const float* __restrict__ bih1, const float* __restrict__ bhh1,
                            const _Float16* __restrict__ W0p, const _Float16* __restrict__ W1p,
                            _Float16* __restrict__ h0q, _Float16* __restrict__ h2q,
                            unsigned* __restrict__ sy)
{
  extern __shared__ float dynls[];                 // gbufT[8][32][65] = 66,560 B
  float (*gbufT)[32][65] = (float(*)[32][65])dynls;
  __shared__ float cst[512];
  __shared__ float biasl[32];
  __shared__ _Float16 htmp[512];

  const int tid  = threadIdx.x;
  const int wg   = blockIdx.x;
  const int lay  = (wg >> 3) & 1;                  // interleaved across XCDs
  const int wgl  = ((wg >> 4) << 3) | (wg & 7);
  const int lane = tid & 63;
  const int kg   = tid >> 6;
  const int quad = lane >> 4;
  const int l15  = lane & 15;
  const int sub  = wgl >> 5;
  const int lofs = (l15 * 4 + quad) * 8;

  if (tid < 32) {
    const int src = ((tid >> 3) << 10) + wgl * 8 + (tid & 7);
    biasl[tid] = lay ? (bih1[src] + bhh1[src]) : (bih0[src] + bhh0[src]);
  }
  cst[tid] = 0.f;
  __syncthreads();

  // flat barrier: counter sy[0|16]; release flags sy[128|256 + i*16]
  auto barrier_step = [&](int n) {
    __syncthreads();
    if (tid == 0) {
      const unsigned e = (unsigned)n + 1u;
      if (lay == 0) {      // slot-reuse admission: all L1 finished step n-3
        while ((int)ld_flag(sy + 256 + sub * 16) < n - 2) __builtin_amdgcn_s_sleep(1);
      } else {             // data admission: h0(n) fully published
        while (ld_flag(sy + 128 + sub * 16) < (unsigned)(n + 2)) __builtin_amdgcn_s_sleep(1);
      }
      unsigned* cnt = sy + (lay ? 16 : 0);
      const unsigned prev = __hip_atomic_fetch_add(cnt, 1u, __ATOMIC_RELAXED,
                                                   __HIP_MEMORY_SCOPE_AGENT);
      if (prev == 128u * e - 1u) {
        unsigned* fl = sy + (lay ? 256 : 128);
#pragma unroll
        for (int i = 0; i < 4; ++i)
          __hip_atomic_store(fl + i * 16, e, __ATOMIC_RELAXED, __HIP_MEMORY_SCOPE_AGENT);
      }
      while (ld_flag(sy + (lay ? 256 : 128) + sub * 16) < e) __builtin_amdgcn_s_sleep(1);
    }
    __syncthreads();
    asm volatile("" ::: "memory");
  };

  auto dump = [&](const f4 (&acc)[4][2]) {
#pragma unroll
    for (int r = 0; r < 4; ++r)
#pragma unroll
      for (int c = 0; c < 2; ++c)
        *(f4*)&gbufT[kg][c * 16 + l15][r * 16 + quad * 4] = acc[r][c];
  };

  auto pointwise_publish = [&](_Float16* wr) {
    __syncthreads();
    if (tid < 128) {
      const int jh = tid >> 4, b4 = tid & 15;
      f4 gs[4];
#pragma unroll
      for (int gate = 0; gate < 4; ++gate) {
        const float bv = biasl[gate * 8 + jh];
        f4 sv = {bv, bv, bv, bv};
#pragma unroll
        for (int g = 0; g < 8; ++g)
          sv += *(const f4*)&gbufT[g][gate * 8 + jh][b4 * 4];
        gs[gate] = sv;
      }
      f4 cold = *(const f4*)&cst[jh * 64 + b4 * 4];
      f4 cnew;
      _Float16 hq[4];
#pragma unroll
      for (int i = 0; i < 4; ++i) {
        const float si = sigm(gs[0][i]);
        const float sf = sigm(gs[1][i]);
        const float tg = tanh_fast(gs[2][i]);
        const float so = sigm(gs[3][i]);
        const float cn = sf * cold[i] + si * tg;
        cnew[i] = cn;
        hq[i] = (_Float16)(so * tanh_fast(cn));
      }
      *(f4*)&cst[jh * 64 + b4 * 4] = cnew;
      _Float16* hd = htmp + jh * 64 + b4 * 4;
      hd[0] = hq[0]; hd[1] = hq[1]; hd[2] = hq[2]; hd[3] = hq[3];
    }
    __syncthreads();
    if (tid < 64) {
      union { h8 v; _Float16 h[8]; } rr;
#pragma unroll
      for (int jh = 0; jh < 8; ++jh) rr.h[jh] = htmp[jh * 64 + tid];
      _Float16* q = wr + (wgl >> 2) * 2048 + (tid >> 4) * 512
                       + ((tid & 15) * 4 + (wgl & 3)) * 8;
      vstore16(q, rr.v);
    }
  };

  if (lay == 0) {
    const _Float16* wpk = W0p + (long)wgl * 40960;
    const int c0 = kg * 5;
    h8 Bw[5][2];                                   // weights live in VGPRs
#pragma unroll
    for (int i = 0; i < 5; ++i) {
      const _Float16* bp = wpk + (c0 + i) * 1024 + lofs;
      Bw[i][0] = *(const h8*)bp;
      Bw[i][1] = *(const h8*)(bp + 512);
    }
    for (int n = 0; n < 513; ++n) {
      barrier_step(n);
      if (n >= 512) continue;
      const _Float16* h0rd = h0q + ((n - 1) & 3) * 65536;
      const _Float16* xt = XP ? (xpk + (long)n * 16384) : nullptr;
      f4 acc[4][2] = {};
      h8 Aa[3][4], Ab[2][4];
#pragma unroll
      for (int i = 0; i < 3; ++i) loadA0<XP>(c0 + i, x, xt, n, h0rd, lofs, l15, quad, Aa[i]);
#pragma unroll
      for (int i = 0; i < 2; ++i) loadA0<XP>(c0 + 3 + i, x, xt, n, h0rd, lofs, l15, quad, Ab[i]);
      __builtin_amdgcn_sched_barrier(0);
#pragma unroll
      for (int i = 0; i < 3; ++i) consume(Aa[i], Bw[i][0], Bw[i][1], acc);
#pragma unroll
      for (int i = 0; i < 2; ++i) consume(Ab[i], Bw[3 + i][0], Bw[3 + i][1], acc);
      dump(acc);
      pointwise_publish(h0q + (n & 3) * 65536);
    }
  } else {
    const _Float16* wpk = W1p + (long)wgl * 65536;
    const int c0 = kg * 8;
    h8 Bw[8][2];
#pragma unroll
    for (int i = 0; i < 8; ++i) {
      const _Float16* bp = wpk + (c0 + i) * 1024 + lofs;
      Bw[i][0] = *(const h8*)bp;
      Bw[i][1] = *(const h8*)(bp + 512);
    }
    for (int n = 0; n < 512; ++n) {
      barrier_step(n);
      const _Float16* h0rd = h0q + (n & 3) * 65536;          // h0(n)
      const _Float16* h2rd = h2q + ((n - 1) & 1) * 65536;    // h2(n-1)
      f4 acc[4][2] = {};
      h8 Aa[4][4], Ab[4][4];
#pragma unroll
      for (int i = 0; i < 4; ++i) loadA1(c0 + i, h0rd, h2rd, lofs, Aa[i]);
#pragma unroll
      for (int i = 0; i < 4; ++i) loadA1(c0 + 4 + i, h0rd, h2rd, lofs, Ab[i]);
      __builtin_amdgcn_sched_barrier(0);
#pragma unroll
      for (int i = 0; i < 4; ++i) consume(Aa[i], Bw[i][0], Bw[i][1], acc);
#pragma unroll
      for (int i = 0; i < 4; ++i) consume(Ab[i], Bw[4 + i][0], Bw[4 + i][1], acc);
      dump(acc);
      pointwise_publish(h2q + (n & 1) * 65536);
    }
  }
}

// ---------------------------------------------------------------------------
__global__ void head_kernel(const _Float16* __restrict__ h2s, const float* __restrict__ Wh,
                            const float* __restrict__ bh, float* __restrict__ out)
{
  const int blk = blockIdx.x;            // 64*24
  const int b = blk / 24, j = blk % 24;
  const int lane = threadIdx.x;          // 64
  float sum = 0.f;
#pragma unroll
  for (int k0 = 0; k0 < 1024; k0 += 64) {
    const int hid = k0 + lane;
    const float hv = (float)h2s[(hid >> 5) * 2048 + (b >> 4) * 512
                                + ((b & 15) * 4 + ((hid >> 3) & 3)) * 8 + (hid & 7)];
    sum += hv * Wh[(long)j * 1024 + hid];
  }
#pragma unroll
  for (int off = 32; off > 0; off >>= 1)
    sum += __shfl_down(sum, off, 64);
  if (lane == 0) out[b * 24 + j] = sum + bh[j];
}

// ---------------------------------------------------------------------------
extern "C" void kernel_launch(void* const* d_in, const int* in_sizes, int n_in,
                              void* d_out, int out_size, void* d_ws, size_t ws_size,
                              hipStream_t stream)
{
  const float* x    = (const float*)d_in[0];
  const float* Wih0 = (const float*)d_in[1];
  const float* Whh0 = (const float*)d_in[2];
  const float* bih0 = (const float*)d_in[3];
  const float* bhh0 = (const float*)d_in[4];
  const float* Wih1 = (const float*)d_in[5];
  const float* Whh1 = (const float*)d_in[6];
  const float* bih1 = (const float*)d_in[7];
  const float* bhh1 = (const float*)d_in[8];
  const float* Whd  = (const float*)d_in[9];
  const float* bhd  = (const float*)d_in[10];

  char* ws = (char*)d_ws;
  _Float16* W0p     = (_Float16*)(ws + WS_W0PACK);
  _Float16* W1p     = (_Float16*)(ws + WS_W1PACK);
  _Float16* h0q     = (_Float16*)(ws + WS_H0Q);
  _Float16* h2q     = (_Float16*)(ws + WS_H2Q);
  unsigned* sync_ws = (unsigned*)(ws + WS_SYNC);
  float* out = (float*)d_out;

  const bool use_xpk = (ws_size >= WS_XPK_END);
  _Float16* xpk = use_xpk ? (_Float16*)(ws + WS_XPK) : nullptr;

  prep_kernel<<<dim3(1024), dim3(256), 0, stream>>>(
      x, Wih0, Whh0, Wih1, Whh1, W0p, W1p, xpk,
      (unsigned*)(ws + WS_H0Q), sync_ws);

  // ~3.3 KB static + 81920 B dynamic LDS -> 1 WG/CU -> 256 WGs co-resident.
  if (use_xpk)
    lstm_kernel<true><<<dim3(256), dim3(512), 81920, stream>>>(
        x, xpk, bih0, bhh0, bih1, bhh1, W0p, W1p, h0q, h2q, sync_ws);
  else
    lstm_kernel<false><<<dim3(256), dim3(512), 81920, stream>>>(
        x, nullptr, bih0, bhh0, bih1, bhh1, W0p, W1p, h0q, h2q, sync_ws);

  head_kernel<<<dim3(64 * 24), dim3(64), 0, stream>>>(
      h2q + 65536, Whd, bhd, out);
}

// Round 5
// 4843.124 us; speedup vs baseline: 1.5876x; 1.5876x over previous
//
#include <hip/hip_runtime.h>

// ============================================================================
// 2-layer LSTM (B=64,T=512,I=256,H=1024) + head. Persistent kernel, R5.
//
// R5 vs R4 (14.6 us/stage, unchanged by weight-traffic removal => floor =
// h-broadcast MALL service + exposed flag/barrier RTT chains):
//  * 4-way BATCH SPLIT: WG = (lay, bg, cs) = 16 batches x 128 cols.
//    h-read volume 48 -> 12 MB/stage. Weights (320/512 KB per WG) stream
//    from XCD-local L2: wg decode puts only 8 col-slices (3.3 MB) per XCD
//    under the %8 block->XCD mapping.
//  * DATAFLOW FLAGS, not top-of-loop barriers: producers arrive AFTER
//    publish (2-level spread counters -> 16 spread flag lines); consumers
//    spin at point-of-use. L1 hides the h2-flag detect behind its
//    flag-independent h0-part GEMM. FIFO: h0q 4 slots, h2q 2 slots.
//  * Pipelined 2-deep chunk loop (B from L2, A from MALL), conflict-free
//    gbufT[8][128][20] reduce, 16B-aligned.
//
// Workspace (44,834,816 B):
//   0         W0p  fp16 [32 cs][40 c][8 nt][512]   10,485,760
//   10485760  W1p  fp16 [32 cs][64 c][8 nt][512]   16,777,216
//   27262976  h0q  fp16 4 slots x [32 c][4 bg][512]   524,288
//   27787264  h2q  fp16 2 slots x same                262,144
//   28049408  sync uint[2048]                           8,192
//   28057600  xpk  fp16 [512 t][8 c][4 bg][512]    16,777,216
// ============================================================================

typedef _Float16 h8 __attribute__((ext_vector_type(8)));
typedef float    f4 __attribute__((ext_vector_type(4)));
typedef unsigned long long u64;

#define WS_W0P   0
#define WS_W1P   10485760
#define WS_H0Q   27262976
#define WS_H2Q   27787264
#define WS_SYNC  28049408
#define WS_XPK   28057600
#define WS_XPK_END 44834816ULL

static __device__ __forceinline__ float sigm(float v) { return 1.f / (1.f + __expf(-v)); }
static __device__ __forceinline__ float tanh_fast(float v) {
  const float e = __expf(2.f * v);
  return 1.f - 2.f / (e + 1.f);
}
static __device__ __forceinline__ h8 vload16(const _Float16* p) {
  return *(const volatile h8*)p;          // coherent (MALL) 16B load
}
static __device__ __forceinline__ void vstore16(_Float16* p, h8 v) {
  *(volatile h8*)p = v;                   // coherent (MALL) 16B store
}

// ---------------------------------------------------------------------------
__global__ void prep_kernel(const float* __restrict__ x,
                            const float* __restrict__ Wih0, const float* __restrict__ Whh0,
                            const float* __restrict__ Wih1, const float* __restrict__ Whh1,
                            _Float16* __restrict__ W0p, _Float16* __restrict__ W1p,
                            _Float16* __restrict__ xpk,
                            unsigned* __restrict__ hz, unsigned* __restrict__ sync_ws)
{
  const long tid0 = (long)blockIdx.x * blockDim.x + threadIdx.x;
  const long np   = (long)gridDim.x * blockDim.x;

  // W0p: e = ((cs*40 + c)*8 + nt)*512 + l15*32 + quad*8 + j
  for (long e = tid0; e < 5242880; e += np) {
    const int j = e & 7, quad = (e >> 3) & 3, l15 = (e >> 5) & 15, nt = (e >> 9) & 7;
    const int r = (int)(e >> 12);
    const int c = r % 40, cs = r / 40;
    const int col = nt * 16 + l15;
    const int row = (col >> 5) * 1024 + cs * 32 + (col & 31);
    const int k = c * 32 + quad * 8 + j;
    const float v = (k < 256) ? Wih0[(long)row * 256 + k] : Whh0[(long)row * 1024 + k - 256];
    W0p[e] = (_Float16)v;
  }
  // W1p: r = cs*64 + c
  for (long e = tid0; e < 8388608; e += np) {
    const int j = e & 7, quad = (e >> 3) & 3, l15 = (e >> 5) & 15, nt = (e >> 9) & 7;
    const int r = (int)(e >> 12);
    const int c = r & 63, cs = r >> 6;
    const int col = nt * 16 + l15;
    const int row = (col >> 5) * 1024 + cs * 32 + (col & 31);
    const int k = c * 32 + quad * 8 + j;
    const float v = (k < 1024) ? Wih1[(long)row * 1024 + k] : Whh1[(long)row * 1024 + k - 1024];
    W1p[e] = (_Float16)v;
  }
  // xpk: e = ((t*8 + c)*4 + bg)*512 + b16*32 + k32
  if (xpk) {
    for (long e = tid0; e < 8388608; e += np) {
      const int k32 = e & 31, b16 = (e >> 5) & 15, bg = (e >> 9) & 3;
      const int c = (e >> 11) & 7;
      const int t = (int)(e >> 14);
      const int b = bg * 16 + b16, k = c * 32 + k32;
      xpk[e] = (_Float16)x[(long)b * 131072 + (long)t * 256 + k];
    }
  }
  for (long e = tid0; e < 196608; e += np) hz[e] = 0u;   // h0q + h2q
  if (tid0 < 2048) sync_ws[tid0] = 0u;
}

// ---------------------------------------------------------------------------
// sync layout (uint idx): per layer base = lay*1024:
//   grp counters: base + g*16 (g 0..15, 8 WGs each)
//   master:       base + 384
//   flags:        base + 512 + i*16 (i 0..15), value = n+1 once h(n) visible
// ---------------------------------------------------------------------------
template<bool XP>
__launch_bounds__(512, 1)
__global__ void lstm_kernel(const float* __restrict__ x, const _Float16* __restrict__ xpk,
                            const float* __restrict__ bih0, const float* __restrict__ bhh0,
                            const float* __restrict__ bih1, const float* __restrict__ bhh1,
                            const _Float16* __restrict__ W0p, const _Float16* __restrict__ W1p,
                            _Float16* __restrict__ h0q, _Float16* __restrict__ h2q,
                            unsigned* __restrict__ sy)
{
  extern __shared__ float gb[];                    // gbufT [8][128][20] = 81,920 B
  __shared__ float cst[512];                       // c-state, slot = tid (hh*16+b16)
  __shared__ float biasl[128];
  __shared__ _Float16 htmp[32 * 18];               // [hh][b16] pad 18

  const int tid = threadIdx.x, wg = blockIdx.x;
  const int xcd = wg & 7, jdec = wg >> 3;
  const int lay = jdec & 1, jj = jdec >> 1;
  const int bg = jj & 3, csl = jj >> 2;
  const int cs = xcd * 4 + csl;                    // col-slice 0..31 (XCD-local)
  const int lidx = bg * 32 + cs;                   // layer-local 0..127
  const int g = lidx >> 3;
  const int lane = tid & 63, kg = tid >> 6;
  const int l15 = lane & 15, quad = lane >> 4;
  const int boff = l15 * 32 + quad * 8;            // B-frag offset in 1024-blk
  const int aoff = bg * 512 + l15 * 32 + quad * 8; // A-frag offset in 2048-blk

  const _Float16* Wp = lay ? (W1p + (long)cs * 262144) : (W0p + (long)cs * 163840);

  if (tid < 128) {
    const int row = (tid >> 5) * 1024 + cs * 32 + (tid & 31);
    biasl[tid] = lay ? (bih1[row] + bhh1[row]) : (bih0[row] + bhh0[row]);
  }
  cst[tid] = 0.f;
  __syncthreads();

  unsigned* const own  = sy + lay * 1024;
  unsigned* const myF  = own + 512 + g * 16;
  unsigned* const otF  = sy + (1 - lay) * 1024 + 512 + g * 16;

  auto spin_ge = [&](const unsigned* p, int target) {
    while ((int)__hip_atomic_load(p, __ATOMIC_RELAXED, __HIP_MEMORY_SCOPE_AGENT) < target)
      __builtin_amdgcn_s_sleep(2);
  };
  auto arrive = [&](unsigned e) {                  // tid==0, after publish drain
    const unsigned prev = __hip_atomic_fetch_add(own + g * 16, 1u,
                            __ATOMIC_RELAXED, __HIP_MEMORY_SCOPE_AGENT);
    if (prev == 8u * e - 1u) {
      const unsigned p2 = __hip_atomic_fetch_add(own + 384, 1u,
                            __ATOMIC_RELAXED, __HIP_MEMORY_SCOPE_AGENT);
      if (p2 == 16u * e - 1u) {
#pragma unroll
        for (int i = 0; i < 16; ++i)
          __hip_atomic_store(own + 512 + i * 16, e,
                             __ATOMIC_RELAXED, __HIP_MEMORY_SCOPE_AGENT);
      }
    }
  };

  auto dump = [&](const f4* acc) {
#pragma unroll
    for (int nt = 0; nt < 8; ++nt)
      *(f4*)&gb[(kg * 128 + nt * 16 + l15) * 20 + quad * 4] = acc[nt];
  };

  auto pointwise_publish = [&](_Float16* wr) {
    __syncthreads();                               // gbufT complete
    {
      const int b16 = tid & 15, hh = tid >> 4;
      float gv[4];
#pragma unroll
      for (int gt = 0; gt < 4; ++gt) {
        float s = biasl[gt * 32 + hh];
#pragma unroll
        for (int k = 0; k < 8; ++k) s += gb[(k * 128 + gt * 32 + hh) * 20 + b16];
        gv[gt] = s;
      }
      const float si = sigm(gv[0]), sf = sigm(gv[1]);
      const float tg = tanh_fast(gv[2]), so = sigm(gv[3]);
      const float cn = sf * cst[tid] + si * tg;
      cst[tid] = cn;
      htmp[hh * 18 + b16] = (_Float16)(so * tanh_fast(cn));
    }
    __syncthreads();
    if (tid < 64) {                                // pack + coherent store
      const int b16 = tid & 15, q = tid >> 4;
      union { h8 v; _Float16 e[8]; } r;
#pragma unroll
      for (int i = 0; i < 8; ++i) r.e[i] = htmp[(q * 8 + i) * 18 + b16];
      vstore16(wr + (cs * 4 + bg) * 512 + b16 * 32 + q * 8, r.v);
    }
    __syncthreads();                               // drain publish (vmcnt0)
  };

  if (lay == 0) {
    const int c0 = kg * 5;
    for (int n = 0; n < 512; ++n) {
      if (tid == 0) { spin_ge(myF, n); spin_ge(otF, n - 3); }  // h0(n-1) ready; slot n&3 free
      __syncthreads();
      const _Float16* h0prev = h0q + ((n - 1) & 3) * 65536;
      const _Float16* xs = XP ? (xpk + (long)n * 16384) : nullptr;

      f4 acc[8] = {};
      h8 Ab[2]; h8 Bb[2][8];
      auto loadAB = [&](int i, int sl) {
        const int c = c0 + i;
        const _Float16* bp = Wp + (long)c * 4096 + boff;
#pragma unroll
        for (int nt = 0; nt < 8; ++nt) Bb[sl][nt] = *(const h8*)(bp + nt * 512);
        if (c < 8) {
          if (XP) Ab[sl] = *(const h8*)(xs + c * 2048 + aoff);
          else {
            const float* q = x + (long)(bg * 16 + l15) * 131072 + (long)n * 256 + c * 32 + quad * 8;
            const f4 v0 = *(const f4*)q;
            const f4 v1 = *(const f4*)(q + 4);
            h8 t;
            t[0]=(_Float16)v0[0]; t[1]=(_Float16)v0[1]; t[2]=(_Float16)v0[2]; t[3]=(_Float16)v0[3];
            t[4]=(_Float16)v1[0]; t[5]=(_Float16)v1[1]; t[6]=(_Float16)v1[2]; t[7]=(_Float16)v1[3];
            Ab[sl] = t;
          }
        } else {
          Ab[sl] = vload16(h0prev + (c - 8) * 2048 + aoff);
        }
      };
      loadAB(0, 0);
#pragma unroll
      for (int i = 0; i < 5; ++i) {
        if (i + 1 < 5) loadAB(i + 1, (i + 1) & 1);
        const h8 A = Ab[i & 1];
#pragma unroll
        for (int nt = 0; nt < 8; ++nt)
          acc[nt] = __builtin_amdgcn_mfma_f32_16x16x32_f16(A, Bb[i & 1][nt], acc[nt], 0, 0, 0);
      }
      dump(acc);
      pointwise_publish(h0q + (n & 3) * 65536);
      if (tid == 0) arrive((unsigned)n + 1u);
    }
  } else {
    const int c0 = kg * 4;
    for (int n = 0; n < 512; ++n) {
      if (tid == 0) spin_ge(otF, n + 1);           // h0(n) visible
      __syncthreads();
      const _Float16* h0cur = h0q + (n & 3) * 65536;
      const _Float16* h2prev = h2q + ((n - 1) & 1) * 65536;

      f4 acc[8] = {};
      h8 Ab[2]; h8 Bb[2][8];
      auto loadAB = [&](const _Float16* hbase, int cw, int cloc, int sl) {
        const _Float16* bp = Wp + (long)cw * 4096 + boff;
#pragma unroll
        for (int nt = 0; nt < 8; ++nt) Bb[sl][nt] = *(const h8*)(bp + nt * 512);
        Ab[sl] = vload16(hbase + cloc * 2048 + aoff);
      };
      // phase A: h0(n) part (chunks c0..c0+3, weights same idx)
      loadAB(h0cur, c0, c0, 0);
#pragma unroll
      for (int i = 0; i < 4; ++i) {
        if (i + 1 < 4) loadAB(h0cur, c0 + i + 1, c0 + i + 1, (i + 1) & 1);
        const h8 A = Ab[i & 1];
#pragma unroll
        for (int nt = 0; nt < 8; ++nt)
          acc[nt] = __builtin_amdgcn_mfma_f32_16x16x32_f16(A, Bb[i & 1][nt], acc[nt], 0, 0, 0);
      }
      // phase B: h2(n-1) part (weights 32+c, A from h2prev) — gated by own flag
      if (tid == 0) spin_ge(myF, n);
      __syncthreads();
      loadAB(h2prev, 32 + c0, c0, 0);
#pragma unroll
      for (int i = 0; i < 4; ++i) {
        if (i + 1 < 4) loadAB(h2prev, 32 + c0 + i + 1, c0 + i + 1, (i + 1) & 1);
        const h8 A = Ab[i & 1];
#pragma unroll
        for (int nt = 0; nt < 8; ++nt)
          acc[nt] = __builtin_amdgcn_mfma_f32_16x16x32_f16(A, Bb[i & 1][nt], acc[nt], 0, 0, 0);
      }
      dump(acc);
      pointwise_publish(h2q + (n & 1) * 65536);
      if (tid == 0) arrive((unsigned)n + 1u);
    }
  }
}

// ---------------------------------------------------------------------------
__global__ void head_kernel(const _Float16* __restrict__ h2s, const float* __restrict__ Wh,
                            const float* __restrict__ bh, float* __restrict__ out)
{
  const int blk = blockIdx.x;            // 64*24
  const int b = blk / 24, j = blk % 24;
  const int lane = threadIdx.x;          // 64
  float sum = 0.f;
#pragma unroll
  for (int k0 = 0; k0 < 1024; k0 += 64) {
    const int hid = k0 + lane;
    const float hv = (float)h2s[((hid >> 5) * 4 + (b >> 4)) * 512 + (b & 15) * 32 + (hid & 31)];
    sum += hv * Wh[(long)j * 1024 + hid];
  }
#pragma unroll
  for (int off = 32; off > 0; off >>= 1)
    sum += __shfl_down(sum, off, 64);
  if (lane == 0) out[b * 24 + j] = sum + bh[j];
}

// ---------------------------------------------------------------------------
extern "C" void kernel_launch(void* const* d_in, const int* in_sizes, int n_in,
                              void* d_out, int out_size, void* d_ws, size_t ws_size,
                              hipStream_t stream)
{
  const float* x    = (const float*)d_in[0];
  const float* Wih0 = (const float*)d_in[1];
  const float* Whh0 = (const float*)d_in[2];
  const float* bih0 = (const float*)d_in[3];
  const float* bhh0 = (const float*)d_in[4];
  const float* Wih1 = (const float*)d_in[5];
  const float* Whh1 = (const float*)d_in[6];
  const float* bih1 = (const float*)d_in[7];
  const float* bhh1 = (const float*)d_in[8];
  const float* Whd  = (const float*)d_in[9];
  const float* bhd  = (const float*)d_in[10];

  char* ws = (char*)d_ws;
  _Float16* W0p     = (_Float16*)(ws + WS_W0P);
  _Float16* W1p     = (_Float16*)(ws + WS_W1P);
  _Float16* h0q     = (_Float16*)(ws + WS_H0Q);
  _Float16* h2q     = (_Float16*)(ws + WS_H2Q);
  unsigned* sync_ws = (unsigned*)(ws + WS_SYNC);
  float* out = (float*)d_out;

  const bool use_xpk = (ws_size >= WS_XPK_END);
  _Float16* xpk = use_xpk ? (_Float16*)(ws + WS_XPK) : nullptr;

  prep_kernel<<<dim3(2048), dim3(256), 0, stream>>>(
      x, Wih0, Whh0, Wih1, Whh1, W0p, W1p, xpk,
      (unsigned*)(ws + WS_H0Q), sync_ws);

  // static ~3.7 KB + dynamic 81,920 B LDS -> 1 WG/CU -> 256 WGs co-resident.
  if (use_xpk)
    lstm_kernel<true><<<dim3(256), dim3(512), 81920, stream>>>(
        x, xpk, bih0, bhh0, bih1, bhh1, W0p, W1p, h0q, h2q, sync_ws);
  else
    lstm_kernel<false><<<dim3(256), dim3(512), 81920, stream>>>(
        x, nullptr, bih0, bhh0, bih1, bhh1, W0p, W1p, h0q, h2q, sync_ws);

  head_kernel<<<dim3(64 * 24), dim3(64), 0, stream>>>(
      h2q + 65536, Whd, bhd, out);   // h2(511), slot 511&1 = 1
}